// Round 1
// baseline (339.256 us; speedup 1.0000x reference)
//
#include <hip/hip_runtime.h>

typedef unsigned short u16;
typedef __attribute__((ext_vector_type(8))) short s8;   // 8 bf16 (4 VGPR) MFMA frag
typedef __attribute__((ext_vector_type(4))) float f4;   // 4 f32 acc frag

#define B_  8
#define C_  64
#define H_  128
#define W_  128
#define HW_ (H_*W_)
#define PITCH 72     // LDS shorts per pixel (144 B rows, 16B-aligned, uniform bank spread)
#define WSZ 36864    // elems of one transformed weight tensor [9][64][64]

// tile: 8 rows x 16 cols output, halo 10 x 18. 1024 blocks -> 4 blocks/CU resident.

// f32 -> bf16 bits, round-to-nearest-even (finite only)
static __device__ __forceinline__ u16 f2bu(float f) {
    union { float f; unsigned u; } c; c.f = f;
    unsigned u = c.u;
    u += 0x7fffu + ((u >> 16) & 1u);
    return (u16)(u >> 16);
}
static __device__ __forceinline__ float bu2f(u16 u) {
    union { unsigned u; float f; } c; c.u = ((unsigned)u) << 16; return c.f;
}

// ---------- transpose+cast: [b][c][h][w] f32 -> [b][h][w][c] bf16 ----------
__global__ __launch_bounds__(256) void transpose2(
    const float* __restrict__ x, const float* __restrict__ edge,
    u16* __restrict__ x_t, u16* __restrict__ edge_t)
{
    __shared__ float s[16][68];
    const int t  = threadIdx.x;
    const int h  = blockIdx.x >> 3;
    const int w0 = (blockIdx.x & 7) * 16;
    const int b  = blockIdx.y;
    const float* src = blockIdx.z ? edge : x;
    u16* dst = blockIdx.z ? edge_t : x_t;
    {
        int c = t >> 2, wq = t & 3;
        float4 v = *(const float4*)(src + ((size_t)b*C_ + c)*HW_ + h*W_ + w0 + wq*4);
        s[wq*4+0][c] = v.x; s[wq*4+1][c] = v.y; s[wq*4+2][c] = v.z; s[wq*4+3][c] = v.w;
    }
    __syncthreads();
    {
        int w = t >> 4, cg = t & 15;
        float4 v = *(const float4*)(&s[w][cg*4]);
        ushort4 o; o.x = f2bu(v.x); o.y = f2bu(v.y); o.z = f2bu(v.z); o.w = f2bu(v.w);
        *(ushort4*)(dst + ((size_t)b*HW_ + h*W_ + w0 + w)*64 + cg*4) = o;
    }
}

// ---------- weight transform: 4x [o][c][3][3] f32 -> [cid][p][o][c] bf16 ----------
__global__ __launch_bounds__(256) void wt_all(
    const float* __restrict__ w0, const float* __restrict__ w1,
    const float* __restrict__ w2, const float* __restrict__ w3,
    u16* __restrict__ dst)
{
    int idx = blockIdx.x*256 + threadIdx.x;            // 0..36863
    int cid = blockIdx.y;
    const float* w = (cid == 0) ? w0 : (cid == 1) ? w1 : (cid == 2) ? w2 : w3;
    int p = idx >> 12, o = (idx >> 6) & 63, c = idx & 63;
    dst[(size_t)cid*WSZ + idx] = f2bu(w[((size_t)o*64 + c)*9 + p]);
}

// ---------- helpers for the fused kernel ----------
static __device__ __forceinline__ void stage_tile(
    u16* __restrict__ s_t, const u16* __restrict__ src, int b, int th0, int tw0, int t)
{
    for (int i = t; i < 10*18*8; i += 256) {
        int pix = i >> 3, ch = i & 7;
        int rr = pix / 18, ww = pix - rr*18;
        int gr = th0 + rr - 1, gw = tw0 + ww - 1;
        uint4 v = {0u,0u,0u,0u};
        if ((unsigned)gr < (unsigned)H_ && (unsigned)gw < (unsigned)W_)
            v = *(const uint4*)(src + ((size_t)b*HW_ + gr*W_ + gw)*64 + ch*8);
        *(uint4*)(&s_t[pix*PITCH + ch*8]) = v;
    }
}

// conv core: D = sum_p [kern_p ⊙] W_p[32och,64c] x X_p[64c,64px], f32 acc, bias init.
// wave (wvM,wvN): och half wvM, pixel rows wvN*4+nf; frag maps carried over (verified).
template<bool PAC>
static __device__ __forceinline__ void conv_core(
    const u16* __restrict__ s_t, const float* __restrict__ s_k,
    const u16* __restrict__ w, const float* __restrict__ bias,
    f4 acc[2][4], int wvM, int wvN, int ln, int quad)
{
#pragma unroll
    for (int mf = 0; mf < 2; ++mf) {
        f4 bv;
#pragma unroll
        for (int r = 0; r < 4; ++r) bv[r] = bias[wvM*32 + mf*16 + quad*4 + r];
#pragma unroll
        for (int nf = 0; nf < 4; ++nf) acc[mf][nf] = bv;
    }

#pragma unroll
    for (int p = 0; p < 9; ++p) {
        const int dr = p / 3, dc = p - dr*3;
        s8 a[2][2];
#pragma unroll
        for (int mf = 0; mf < 2; ++mf)
#pragma unroll
            for (int kc = 0; kc < 2; ++kc)
                a[mf][kc] = *(const s8*)(w + (((size_t)p*64 + wvM*32 + mf*16 + ln)*64 + kc*32 + quad*8));
        s8 bfr[4][2];
#pragma unroll
        for (int nf = 0; nf < 4; ++nf) {
            const u16* base = &s_t[((wvN*4 + nf + dr)*18 + ln + dc)*PITCH];
#pragma unroll
            for (int kc = 0; kc < 2; ++kc)
                bfr[nf][kc] = *(const s8*)(base + kc*32 + quad*8);
        }
        if (PAC) {
            float kv[4];
#pragma unroll
            for (int nf = 0; nf < 4; ++nf)
                kv[nf] = s_k[p*128 + (wvN*4 + nf)*16 + ln];
#pragma unroll
            for (int mf = 0; mf < 2; ++mf)
#pragma unroll
                for (int nf = 0; nf < 4; ++nf) {
                    f4 d = {0.f, 0.f, 0.f, 0.f};
                    d = __builtin_amdgcn_mfma_f32_16x16x32_bf16(a[mf][0], bfr[nf][0], d, 0, 0, 0);
                    d = __builtin_amdgcn_mfma_f32_16x16x32_bf16(a[mf][1], bfr[nf][1], d, 0, 0, 0);
                    acc[mf][nf] += kv[nf] * d;
                }
        } else {
#pragma unroll
            for (int mf = 0; mf < 2; ++mf)
#pragma unroll
                for (int nf = 0; nf < 4; ++nf) {
                    acc[mf][nf] = __builtin_amdgcn_mfma_f32_16x16x32_bf16(a[mf][0], bfr[nf][0], acc[mf][nf], 0, 0, 0);
                    acc[mf][nf] = __builtin_amdgcn_mfma_f32_16x16x32_bf16(a[mf][1], bfr[nf][1], acc[mf][nf], 0, 0, 0);
                }
        }
    }
}

// epilogue: bf16 NHWC with relu (stage 1)
static __device__ __forceinline__ void store_t(
    u16* __restrict__ out, f4 acc[2][4], int b, int th0, int tw0,
    int wvM, int wvN, int ln, int quad)
{
#pragma unroll
    for (int mf = 0; mf < 2; ++mf)
#pragma unroll
        for (int nf = 0; nf < 4; ++nf) {
            f4 v = acc[mf][nf];
            ushort4 o;
            o.x = f2bu(fmaxf(v[0], 0.f)); o.y = f2bu(fmaxf(v[1], 0.f));
            o.z = f2bu(fmaxf(v[2], 0.f)); o.w = f2bu(fmaxf(v[3], 0.f));
            size_t pix = (size_t)b*HW_ + (th0 + wvN*4 + nf)*W_ + tw0 + ln;
            *(ushort4*)(out + pix*64 + wvM*32 + mf*16 + quad*4) = o;
        }
}

// epilogue: f32 NCHW + residual from bf16 NHWC (stage 2)
static __device__ __forceinline__ void store_f(
    float* __restrict__ out, const u16* __restrict__ resid_t,
    f4 acc[2][4], int b, int th0, int tw0, int wvM, int wvN, int ln, int quad)
{
#pragma unroll
    for (int mf = 0; mf < 2; ++mf)
#pragma unroll
        for (int nf = 0; nf < 4; ++nf) {
            size_t pix = (size_t)b*HW_ + (th0 + wvN*4 + nf)*W_ + tw0 + ln;
            ushort4 rv = *(const ushort4*)(resid_t + pix*64 + wvM*32 + mf*16 + quad*4);
            float rr[4] = {bu2f(rv.x), bu2f(rv.y), bu2f(rv.z), bu2f(rv.w)};
#pragma unroll
            for (int r = 0; r < 4; ++r) {
                int och = wvM*32 + mf*16 + quad*4 + r;
                out[((size_t)b*C_ + och)*HW_ + (th0 + wvN*4 + nf)*W_ + tw0 + ln]
                    = acc[mf][nf][r] + rr[r];
            }
        }
}

// ---------- fused stage: gauss(inA) + convA(plain, inA) + convB(PAC, inB | guide=inA) ----------
// STAGE1: relu + bf16 NHWC outs.   STAGE2: f32 NCHW outs + residuals.
template<bool STAGE1>
__global__ __launch_bounds__(256, 4) void fused_stage(
    const u16* __restrict__ inA_t, const u16* __restrict__ inB_t,
    const u16* __restrict__ wA, const u16* __restrict__ wB,
    const float* __restrict__ biasA, const float* __restrict__ biasB,
    const u16* __restrict__ residA_t, const u16* __restrict__ residB_t,
    u16* __restrict__ outA_t, u16* __restrict__ outB_t,
    float* __restrict__ outA_f, float* __restrict__ outB_f)
{
    __shared__ u16   s_t[10*18*PITCH];   // 25920 B
    __shared__ float s_k[9*128];         //  4608 B  (30.5 KB total -> 4 blocks/CU)

    const int t    = threadIdx.x;
    const int b    = blockIdx.y;
    const int th0  = (blockIdx.x >> 3) * 8;
    const int tw0  = (blockIdx.x & 7) * 16;
    const int wv   = t >> 6;
    const int wvM  = wv >> 1;            // och half (0..1)
    const int wvN  = wv & 1;             // pixel-row half (0..1)
    const int lane = t & 63;
    const int ln   = lane & 15;
    const int quad = lane >> 4;

    // ---- phase 1: stage guide/inA tile ----
    stage_tile(s_t, inA_t, b, th0, tw0, t);
    __syncthreads();

    // ---- phase 2a: gaussian kernel from inA tile -> s_k ----
    // 128 pixels, 256 threads: thread owns pixel (t&127) and taps p0..p0+np-1.
    {
        const int px   = t & 127;
        const int half = t >> 7;
        const int p0   = half ? 5 : 0;
        const int np   = half ? 4 : 5;
        const int py   = px >> 4, pxc = px & 15;
        float d2[5];
#pragma unroll
        for (int k = 0; k < 5; ++k) d2[k] = 0.f;
        const u16* cb = &s_t[((py+1)*18 + (pxc+1))*PITCH];
#pragma unroll 1
        for (int co = 0; co < 8; ++co) {
            s8 c8 = *(const s8*)(cb + co*8);
            float cf[8];
#pragma unroll
            for (int j = 0; j < 8; ++j) cf[j] = bu2f((u16)c8[j]);
#pragma unroll
            for (int k = 0; k < 5; ++k) {
                if (k < np) {
                    int p = p0 + k;
                    int dr = p / 3, dc = p - dr*3;
                    s8 n8 = *(const s8*)(&s_t[((py + dr)*18 + pxc + dc)*PITCH + co*8]);
#pragma unroll
                    for (int j = 0; j < 8; ++j) {
                        float d = bu2f((u16)n8[j]) - cf[j];
                        d2[k] += d * d;
                    }
                }
            }
        }
#pragma unroll
        for (int k = 0; k < 5; ++k)
            if (k < np) s_k[(p0+k)*128 + px] = __expf(-0.5f * d2[k]);
    }

    // ---- phase 2b: convA (plain) on inA tile ----
    {
        f4 acc[2][4];
        conv_core<false>(s_t, nullptr, wA, biasA, acc, wvM, wvN, ln, quad);
        if (STAGE1) store_t(outA_t, acc, b, th0, tw0, wvM, wvN, ln, quad);
        else        store_f(outA_f, residA_t, acc, b, th0, tw0, wvM, wvN, ln, quad);
    }

    // ---- phase 3: restage with inB tile (also orders s_k writes before reads) ----
    __syncthreads();
    stage_tile(s_t, inB_t, b, th0, tw0, t);
    __syncthreads();

    // ---- phase 4: convB (PAC with s_k) on inB tile ----
    {
        f4 acc[2][4];
        conv_core<true>(s_t, s_k, wB, biasB, acc, wvM, wvN, ln, quad);
        if (STAGE1) store_t(outB_t, acc, b, th0, tw0, wvM, wvN, ln, quad);
        else        store_f(outB_f, residB_t, acc, b, th0, tw0, wvM, wvN, ln, quad);
    }
}

extern "C" void kernel_launch(void* const* d_in, const int* in_sizes, int n_in,
                              void* d_out, int out_size, void* d_ws, size_t ws_size,
                              hipStream_t stream)
{
    const float* x      = (const float*)d_in[0];
    const float* edge   = (const float*)d_in[1];
    const float* w_pac1 = (const float*)d_in[2];
    const float* b_pac1 = (const float*)d_in[3];
    const float* w_pac2 = (const float*)d_in[4];
    const float* b_pac2 = (const float*)d_in[5];
    const float* w_e1   = (const float*)d_in[6];
    const float* b_e1   = (const float*)d_in[7];
    const float* w_e2   = (const float*)d_in[8];
    const float* b_e2   = (const float*)d_in[9];

    float* out_sr   = (float*)d_out;
    float* out_edge = out_sr + (size_t)B_*C_*HW_;

    const size_t NT = (size_t)B_*HW_*64;
    // ws (67.4 MB): all intermediates live here — nothing parked in d_out.
    u16* x_t         = (u16*)d_ws;
    u16* edge_t      = x_t + NT;
    u16* res_edge1_t = edge_t + NT;
    u16* res_sr1_t   = res_edge1_t + NT;
    u16* w_t         = res_sr1_t + NT;    // [4][9][64][64]: 0=e1, 1=pac1, 2=e2, 3=pac2

    dim3 blk(256);

    transpose2<<<dim3(H_*8, B_, 2), blk, 0, stream>>>(x, edge, x_t, edge_t);
    wt_all<<<dim3(144, 4), blk, 0, stream>>>(w_e1, w_pac1, w_e2, w_pac2, w_t);

    // stage 1: gauss(edge)=kern1 (LDS-only) + conv_e1(edge) + pac1(x)
    fused_stage<true ><<<dim3(128, B_), blk, 0, stream>>>(
        edge_t, x_t, w_t + 0*WSZ, w_t + 1*WSZ, b_e1, b_pac1,
        nullptr, nullptr, res_edge1_t, res_sr1_t, nullptr, nullptr);
    // stage 2: gauss(res_edge1)=kern2 + conv_e2(res_edge1)+edge_resid + pac2(res_sr1)+x_resid
    fused_stage<false><<<dim3(128, B_), blk, 0, stream>>>(
        res_edge1_t, res_sr1_t, w_t + 2*WSZ, w_t + 3*WSZ, b_e2, b_pac2,
        edge_t, x_t, nullptr, nullptr, out_edge, out_sr);
}

// Round 2
// 338.178 us; speedup vs baseline: 1.0032x; 1.0032x over previous
//
#include <hip/hip_runtime.h>

typedef unsigned short u16;
typedef __attribute__((ext_vector_type(8))) short s8;   // 8 bf16 (4 VGPR) MFMA frag
typedef __attribute__((ext_vector_type(4))) float f4;   // 4 f32 acc frag

#define B_  8
#define C_  64
#define H_  128
#define W_  128
#define HW_ (H_*W_)
#define PITCH 72     // LDS shorts per pixel (144 B rows, 16B-aligned, uniform bank spread)
#define WSZ 36864    // elems of one transformed weight tensor [9][64][64]

// f32 -> bf16 bits, round-to-nearest-even (finite only)
static __device__ __forceinline__ u16 f2bu(float f) {
    union { float f; unsigned u; } c; c.f = f;
    unsigned u = c.u;
    u += 0x7fffu + ((u >> 16) & 1u);
    return (u16)(u >> 16);
}
static __device__ __forceinline__ float bu2f(u16 u) {
    union { unsigned u; float f; } c; c.u = ((unsigned)u) << 16; return c.f;
}
// f32 <-> f16 bits (for the gaussian kernel LDS store; 2^-11 rel err, well
// below the bf16 quantization already in the data path)
static __device__ __forceinline__ u16 f2h(float f) {
    union { _Float16 h; u16 u; } c; c.h = (_Float16)f; return c.u;
}
static __device__ __forceinline__ float h2f(u16 u) {
    union { u16 u; _Float16 h; } c; c.u = u; return (float)c.h;
}

// ---------- transpose+cast: [b][c][h][w] f32 -> [b][h][w][c] bf16 ----------
__global__ __launch_bounds__(256) void transpose2(
    const float* __restrict__ x, const float* __restrict__ edge,
    u16* __restrict__ x_t, u16* __restrict__ edge_t)
{
    __shared__ float s[16][68];
    const int t  = threadIdx.x;
    const int h  = blockIdx.x >> 3;
    const int w0 = (blockIdx.x & 7) * 16;
    const int b  = blockIdx.y;
    const float* src = blockIdx.z ? edge : x;
    u16* dst = blockIdx.z ? edge_t : x_t;
    {
        int c = t >> 2, wq = t & 3;
        float4 v = *(const float4*)(src + ((size_t)b*C_ + c)*HW_ + h*W_ + w0 + wq*4);
        s[wq*4+0][c] = v.x; s[wq*4+1][c] = v.y; s[wq*4+2][c] = v.z; s[wq*4+3][c] = v.w;
    }
    __syncthreads();
    {
        int w = t >> 4, cg = t & 15;
        float4 v = *(const float4*)(&s[w][cg*4]);
        ushort4 o; o.x = f2bu(v.x); o.y = f2bu(v.y); o.z = f2bu(v.z); o.w = f2bu(v.w);
        *(ushort4*)(dst + ((size_t)b*HW_ + h*W_ + w0 + w)*64 + cg*4) = o;
    }
}

// ---------- weight transform: 4x [o][c][3][3] f32 -> [cid][p][o][c] bf16 ----------
__global__ __launch_bounds__(256) void wt_all(
    const float* __restrict__ w0, const float* __restrict__ w1,
    const float* __restrict__ w2, const float* __restrict__ w3,
    u16* __restrict__ dst)
{
    int idx = blockIdx.x*256 + threadIdx.x;            // 0..36863
    int cid = blockIdx.y;
    const float* w = (cid == 0) ? w0 : (cid == 1) ? w1 : (cid == 2) ? w2 : w3;
    int p = idx >> 12, o = (idx >> 6) & 63, c = idx & 63;
    dst[(size_t)cid*WSZ + idx] = f2bu(w[((size_t)o*64 + c)*9 + p]);
}

// ---------- helpers for the fused kernel ----------
static __device__ __forceinline__ void stage_tile(
    u16* __restrict__ s_t, const u16* __restrict__ src, int b, int th0, int tw0, int t)
{
    for (int i = t; i < 18*18*8; i += 256) {
        int pix = i >> 3, ch = i & 7;
        int rr = pix / 18, ww = pix - rr*18;
        int gr = th0 + rr - 1, gw = tw0 + ww - 1;
        uint4 v = {0u,0u,0u,0u};
        if ((unsigned)gr < (unsigned)H_ && (unsigned)gw < (unsigned)W_)
            v = *(const uint4*)(src + ((size_t)b*HW_ + gr*W_ + gw)*64 + ch*8);
        *(uint4*)(&s_t[pix*PITCH + ch*8]) = v;
    }
}

// conv core: D = sum_p [kern_p ⊙] W_p[64och,64c] x X_p[64c,256px], f32 acc, bias init.
// wave wv owns pixel rows wv*4+nf; frag maps verified previously.
template<bool PAC>
static __device__ __forceinline__ void conv_core(
    const u16* __restrict__ s_t, const u16* __restrict__ s_k,
    const u16* __restrict__ w, const float* __restrict__ bias,
    f4 acc[4][4], int wv, int ln, int quad)
{
#pragma unroll
    for (int mf = 0; mf < 4; ++mf) {
        f4 bv;
#pragma unroll
        for (int r = 0; r < 4; ++r) bv[r] = bias[mf*16 + quad*4 + r];
#pragma unroll
        for (int nf = 0; nf < 4; ++nf) acc[mf][nf] = bv;
    }

#pragma unroll
    for (int p = 0; p < 9; ++p) {
        const int dr = p / 3, dc = p - dr*3;
        s8 a[4][2];
#pragma unroll
        for (int mf = 0; mf < 4; ++mf)
#pragma unroll
            for (int kc = 0; kc < 2; ++kc)
                a[mf][kc] = *(const s8*)(w + (((size_t)p*64 + mf*16 + ln)*64 + kc*32 + quad*8));
        s8 bfr[4][2];
#pragma unroll
        for (int nf = 0; nf < 4; ++nf) {
            const u16* base = &s_t[((wv*4 + nf + dr)*18 + ln + dc)*PITCH];
#pragma unroll
            for (int kc = 0; kc < 2; ++kc)
                bfr[nf][kc] = *(const s8*)(base + kc*32 + quad*8);
        }
        if (PAC) {
            float kv[4];
#pragma unroll
            for (int nf = 0; nf < 4; ++nf)
                kv[nf] = h2f(s_k[p*256 + (wv*4 + nf)*16 + ln]);
#pragma unroll
            for (int mf = 0; mf < 4; ++mf)
#pragma unroll
                for (int nf = 0; nf < 4; ++nf) {
                    f4 d = {0.f, 0.f, 0.f, 0.f};
                    d = __builtin_amdgcn_mfma_f32_16x16x32_bf16(a[mf][0], bfr[nf][0], d, 0, 0, 0);
                    d = __builtin_amdgcn_mfma_f32_16x16x32_bf16(a[mf][1], bfr[nf][1], d, 0, 0, 0);
                    acc[mf][nf] += kv[nf] * d;
                }
        } else {
#pragma unroll
            for (int mf = 0; mf < 4; ++mf)
#pragma unroll
                for (int nf = 0; nf < 4; ++nf) {
                    acc[mf][nf] = __builtin_amdgcn_mfma_f32_16x16x32_bf16(a[mf][0], bfr[nf][0], acc[mf][nf], 0, 0, 0);
                    acc[mf][nf] = __builtin_amdgcn_mfma_f32_16x16x32_bf16(a[mf][1], bfr[nf][1], acc[mf][nf], 0, 0, 0);
                }
        }
    }
}

// epilogue: bf16 NHWC with relu (stage 1)
static __device__ __forceinline__ void store_t(
    u16* __restrict__ out, f4 acc[4][4], int b, int th0, int tw0, int wv, int ln, int quad)
{
#pragma unroll
    for (int mf = 0; mf < 4; ++mf)
#pragma unroll
        for (int nf = 0; nf < 4; ++nf) {
            f4 v = acc[mf][nf];
            ushort4 o;
            o.x = f2bu(fmaxf(v[0], 0.f)); o.y = f2bu(fmaxf(v[1], 0.f));
            o.z = f2bu(fmaxf(v[2], 0.f)); o.w = f2bu(fmaxf(v[3], 0.f));
            size_t pix = (size_t)b*HW_ + (th0 + wv*4 + nf)*W_ + tw0 + ln;
            *(ushort4*)(out + pix*64 + mf*16 + quad*4) = o;
        }
}

// epilogue: f32 NCHW + residual from bf16 NHWC (stage 2)
static __device__ __forceinline__ void store_f(
    float* __restrict__ out, const u16* __restrict__ resid_t,
    f4 acc[4][4], int b, int th0, int tw0, int wv, int ln, int quad)
{
#pragma unroll
    for (int mf = 0; mf < 4; ++mf)
#pragma unroll
        for (int nf = 0; nf < 4; ++nf) {
            size_t pix = (size_t)b*HW_ + (th0 + wv*4 + nf)*W_ + tw0 + ln;
            ushort4 rv = *(const ushort4*)(resid_t + pix*64 + mf*16 + quad*4);
            float rr[4] = {bu2f(rv.x), bu2f(rv.y), bu2f(rv.z), bu2f(rv.w)};
#pragma unroll
            for (int r = 0; r < 4; ++r) {
                int och = mf*16 + quad*4 + r;
                out[((size_t)b*C_ + och)*HW_ + (th0 + wv*4 + nf)*W_ + tw0 + ln]
                    = acc[mf][nf][r] + rr[r];
            }
        }
}

// ---------- fused stage: gauss(inA) + convA(plain, inA) + convB(PAC, inB | guide=inA) ----------
// STAGE1: relu + bf16 NHWC outs.   STAGE2: f32 NCHW outs + residuals.
// LDS 51264 B (s_k stored fp16) -> 3 blocks/CU with __launch_bounds__(256,3).
template<bool STAGE1>
__global__ __launch_bounds__(256, 3) void fused_stage(
    const u16* __restrict__ inA_t, const u16* __restrict__ inB_t,
    const u16* __restrict__ wA, const u16* __restrict__ wB,
    const float* __restrict__ biasA, const float* __restrict__ biasB,
    const u16* __restrict__ residA_t, const u16* __restrict__ residB_t,
    u16* __restrict__ outA_t, u16* __restrict__ outB_t,
    float* __restrict__ outA_f, float* __restrict__ outB_f)
{
    __shared__ u16 s_t[18*18*PITCH];   // 46656 B
    __shared__ u16 s_k[9*256];         //  4608 B  (51.3 KB total -> 3 blocks/CU)

    const int t    = threadIdx.x;
    const int b    = blockIdx.y;
    const int th0  = (blockIdx.x >> 3) * 16;
    const int tw0  = (blockIdx.x & 7) * 16;
    const int wv   = t >> 6;
    const int lane = t & 63;
    const int ln   = lane & 15;
    const int quad = lane >> 4;

    // ---- phase 1: stage guide/inA tile ----
    stage_tile(s_t, inA_t, b, th0, tw0, t);
    __syncthreads();

    // ---- phase 2a: gaussian kernel from inA tile -> s_k (one pixel per thread) ----
    {
        const int px = t & 15, py = t >> 4;
        float d2[9];
#pragma unroll
        for (int p = 0; p < 9; ++p) d2[p] = 0.f;
        const u16* cb = &s_t[((py+1)*18 + (px+1))*PITCH];
#pragma unroll 1
        for (int co = 0; co < 8; ++co) {
            s8 c8 = *(const s8*)(cb + co*8);
            float cf[8];
#pragma unroll
            for (int j = 0; j < 8; ++j) cf[j] = bu2f((u16)c8[j]);
#pragma unroll
            for (int p = 0; p < 9; ++p) {
                s8 n8 = *(const s8*)(&s_t[((py + p/3)*18 + px + p%3)*PITCH + co*8]);
#pragma unroll
                for (int j = 0; j < 8; ++j) {
                    float d = bu2f((u16)n8[j]) - cf[j];
                    d2[p] += d * d;
                }
            }
        }
#pragma unroll
        for (int p = 0; p < 9; ++p)
            s_k[p*256 + py*16 + px] = f2h(__expf(-0.5f * d2[p]));
    }

    // ---- phase 2b: convA (plain) on inA tile ----
    {
        f4 acc[4][4];
        conv_core<false>(s_t, nullptr, wA, biasA, acc, wv, ln, quad);
        if (STAGE1) store_t(outA_t, acc, b, th0, tw0, wv, ln, quad);
        else        store_f(outA_f, residA_t, acc, b, th0, tw0, wv, ln, quad);
    }

    // ---- phase 3: restage with inB tile (also orders s_k writes before reads) ----
    __syncthreads();
    stage_tile(s_t, inB_t, b, th0, tw0, t);
    __syncthreads();

    // ---- phase 4: convB (PAC with s_k) on inB tile ----
    {
        f4 acc[4][4];
        conv_core<true>(s_t, s_k, wB, biasB, acc, wv, ln, quad);
        if (STAGE1) store_t(outB_t, acc, b, th0, tw0, wv, ln, quad);
        else        store_f(outB_f, residB_t, acc, b, th0, tw0, wv, ln, quad);
    }
}

extern "C" void kernel_launch(void* const* d_in, const int* in_sizes, int n_in,
                              void* d_out, int out_size, void* d_ws, size_t ws_size,
                              hipStream_t stream)
{
    const float* x      = (const float*)d_in[0];
    const float* edge   = (const float*)d_in[1];
    const float* w_pac1 = (const float*)d_in[2];
    const float* b_pac1 = (const float*)d_in[3];
    const float* w_pac2 = (const float*)d_in[4];
    const float* b_pac2 = (const float*)d_in[5];
    const float* w_e1   = (const float*)d_in[6];
    const float* b_e1   = (const float*)d_in[7];
    const float* w_e2   = (const float*)d_in[8];
    const float* b_e2   = (const float*)d_in[9];

    float* out_sr   = (float*)d_out;
    float* out_edge = out_sr + (size_t)B_*C_*HW_;

    const size_t NT = (size_t)B_*HW_*64;
    // ws (67.4 MB): all intermediates live here — nothing parked in d_out.
    u16* x_t         = (u16*)d_ws;
    u16* edge_t      = x_t + NT;
    u16* res_edge1_t = edge_t + NT;
    u16* res_sr1_t   = res_edge1_t + NT;
    u16* w_t         = res_sr1_t + NT;    // [4][9][64][64]: 0=e1, 1=pac1, 2=e2, 3=pac2

    dim3 blk(256);

    transpose2<<<dim3(H_*8, B_, 2), blk, 0, stream>>>(x, edge, x_t, edge_t);
    wt_all<<<dim3(144, 4), blk, 0, stream>>>(w_e1, w_pac1, w_e2, w_pac2, w_t);

    // stage 1: gauss(edge)=kern1 (LDS-only) + conv_e1(edge) + pac1(x)
    fused_stage<true ><<<dim3(64, B_), blk, 0, stream>>>(
        edge_t, x_t, w_t + 0*WSZ, w_t + 1*WSZ, b_e1, b_pac1,
        nullptr, nullptr, res_edge1_t, res_sr1_t, nullptr, nullptr);
    // stage 2: gauss(res_edge1)=kern2 + conv_e2(res_edge1)+edge_resid + pac2(res_sr1)+x_resid
    fused_stage<false><<<dim3(64, B_), blk, 0, stream>>>(
        res_edge1_t, res_sr1_t, w_t + 2*WSZ, w_t + 3*WSZ, b_e2, b_pac2,
        edge_t, x_t, nullptr, nullptr, out_edge, out_sr);
}

// Round 3
// 265.160 us; speedup vs baseline: 1.2794x; 1.2754x over previous
//
#include <hip/hip_runtime.h>

typedef unsigned short u16;
typedef __attribute__((ext_vector_type(8))) short s8;   // 8 bf16 (4 VGPR) MFMA frag
typedef __attribute__((ext_vector_type(4))) float f4;   // 4 f32 acc frag

#define B_  8
#define C_  64
#define H_  128
#define W_  128
#define HW_ (H_*W_)
#define PITCH 72     // LDS shorts per pixel (144 B rows, 16B-aligned, uniform bank spread)
#define WSZ 36864    // elems of one transformed weight tensor [9][64][64]
#define STAGE_N 2592 // 18*18*8 uint4 chunks per tile
#define HOLD_K 11    // ceil(2592/256)

// f32 -> bf16 bits, round-to-nearest-even (finite only)
static __device__ __forceinline__ u16 f2bu(float f) {
    union { float f; unsigned u; } c; c.f = f;
    unsigned u = c.u;
    u += 0x7fffu + ((u >> 16) & 1u);
    return (u16)(u >> 16);
}
static __device__ __forceinline__ float bu2f(u16 u) {
    union { unsigned u; float f; } c; c.u = ((unsigned)u) << 16; return c.f;
}

// ---------- transpose+cast: [b][c][h][w] f32 -> [b][h][w][c] bf16 ----------
__global__ __launch_bounds__(256) void transpose2(
    const float* __restrict__ x, const float* __restrict__ edge,
    u16* __restrict__ x_t, u16* __restrict__ edge_t)
{
    __shared__ float s[16][68];
    const int t  = threadIdx.x;
    const int h  = blockIdx.x >> 3;
    const int w0 = (blockIdx.x & 7) * 16;
    const int b  = blockIdx.y;
    const float* src = blockIdx.z ? edge : x;
    u16* dst = blockIdx.z ? edge_t : x_t;
    {
        int c = t >> 2, wq = t & 3;
        float4 v = *(const float4*)(src + ((size_t)b*C_ + c)*HW_ + h*W_ + w0 + wq*4);
        s[wq*4+0][c] = v.x; s[wq*4+1][c] = v.y; s[wq*4+2][c] = v.z; s[wq*4+3][c] = v.w;
    }
    __syncthreads();
    {
        int w = t >> 4, cg = t & 15;
        float4 v = *(const float4*)(&s[w][cg*4]);
        ushort4 o; o.x = f2bu(v.x); o.y = f2bu(v.y); o.z = f2bu(v.z); o.w = f2bu(v.w);
        *(ushort4*)(dst + ((size_t)b*HW_ + h*W_ + w0 + w)*64 + cg*4) = o;
    }
}

// ---------- weight transform: 4x [o][c][3][3] f32 -> [cid][p][o][c] bf16 ----------
__global__ __launch_bounds__(256) void wt_all(
    const float* __restrict__ w0, const float* __restrict__ w1,
    const float* __restrict__ w2, const float* __restrict__ w3,
    u16* __restrict__ dst)
{
    int idx = blockIdx.x*256 + threadIdx.x;            // 0..36863
    int cid = blockIdx.y;
    const float* w = (cid == 0) ? w0 : (cid == 1) ? w1 : (cid == 2) ? w2 : w3;
    int p = idx >> 12, o = (idx >> 6) & 63, c = idx & 63;
    dst[(size_t)cid*WSZ + idx] = f2bu(w[((size_t)o*64 + c)*9 + p]);
}

// ---------- helpers for the fused kernel ----------
static __device__ __forceinline__ void stage_tile(
    u16* __restrict__ s_t, const u16* __restrict__ src, int b, int th0, int tw0, int t)
{
    for (int i = t; i < STAGE_N; i += 256) {
        int pix = i >> 3, ch = i & 7;
        int rr = pix / 18, ww = pix - rr*18;
        int gr = th0 + rr - 1, gw = tw0 + ww - 1;
        uint4 v = {0u,0u,0u,0u};
        if ((unsigned)gr < (unsigned)H_ && (unsigned)gw < (unsigned)W_)
            v = *(const uint4*)(src + ((size_t)b*HW_ + gr*W_ + gw)*64 + ch*8);
        *(uint4*)(&s_t[pix*PITCH + ch*8]) = v;
    }
}

// T14 async-stage split: issue global loads into registers early...
static __device__ __forceinline__ void stage_issue(
    uint4 v[HOLD_K], const u16* __restrict__ src, int b, int th0, int tw0, int t)
{
#pragma unroll
    for (int k = 0; k < HOLD_K; ++k) {
        int i = t + k*256;
        uint4 r = {0u,0u,0u,0u};
        if (k < HOLD_K-1 || i < STAGE_N) {
            int pix = i >> 3, ch = i & 7;
            int rr = pix / 18, ww = pix - rr*18;
            int gr = th0 + rr - 1, gw = tw0 + ww - 1;
            if ((unsigned)gr < (unsigned)H_ && (unsigned)gw < (unsigned)W_)
                r = *(const uint4*)(src + ((size_t)b*HW_ + gr*W_ + gw)*64 + ch*8);
        }
        v[k] = r;
    }
}
// ...and commit them to LDS late (after the consumers of the old tile are done).
static __device__ __forceinline__ void stage_commit(
    const uint4 v[HOLD_K], u16* __restrict__ s_t, int t)
{
#pragma unroll
    for (int k = 0; k < HOLD_K; ++k) {
        int i = t + k*256;
        if (k < HOLD_K-1 || i < STAGE_N) {
            int pix = i >> 3, ch = i & 7;
            *(uint4*)(&s_t[pix*PITCH + ch*8]) = v[k];
        }
    }
}

// conv core: D = sum_p [kern_p ⊙] W_p[64och,64c] x X_p[64c,256px], f32 acc, bias init.
// wave wv owns pixel rows wv*4+nf; frag maps verified previously.
template<bool PAC>
static __device__ __forceinline__ void conv_core(
    const u16* __restrict__ s_t, const float* __restrict__ s_k,
    const u16* __restrict__ w, const float* __restrict__ bias,
    f4 acc[4][4], int wv, int ln, int quad)
{
#pragma unroll
    for (int mf = 0; mf < 4; ++mf) {
        f4 bv;
#pragma unroll
        for (int r = 0; r < 4; ++r) bv[r] = bias[mf*16 + quad*4 + r];
#pragma unroll
        for (int nf = 0; nf < 4; ++nf) acc[mf][nf] = bv;
    }

#pragma unroll
    for (int p = 0; p < 9; ++p) {
        const int dr = p / 3, dc = p - dr*3;
        s8 a[4][2];
#pragma unroll
        for (int mf = 0; mf < 4; ++mf)
#pragma unroll
            for (int kc = 0; kc < 2; ++kc)
                a[mf][kc] = *(const s8*)(w + (((size_t)p*64 + mf*16 + ln)*64 + kc*32 + quad*8));
        s8 bfr[4][2];
#pragma unroll
        for (int nf = 0; nf < 4; ++nf) {
            const u16* base = &s_t[((wv*4 + nf + dr)*18 + ln + dc)*PITCH];
#pragma unroll
            for (int kc = 0; kc < 2; ++kc)
                bfr[nf][kc] = *(const s8*)(base + kc*32 + quad*8);
        }
        if (PAC) {
            float kv[4];
#pragma unroll
            for (int nf = 0; nf < 4; ++nf)
                kv[nf] = s_k[p*256 + (wv*4 + nf)*16 + ln];
#pragma unroll
            for (int mf = 0; mf < 4; ++mf)
#pragma unroll
                for (int nf = 0; nf < 4; ++nf) {
                    f4 d = {0.f, 0.f, 0.f, 0.f};
                    d = __builtin_amdgcn_mfma_f32_16x16x32_bf16(a[mf][0], bfr[nf][0], d, 0, 0, 0);
                    d = __builtin_amdgcn_mfma_f32_16x16x32_bf16(a[mf][1], bfr[nf][1], d, 0, 0, 0);
                    acc[mf][nf] += kv[nf] * d;
                }
        } else {
#pragma unroll
            for (int mf = 0; mf < 4; ++mf)
#pragma unroll
                for (int nf = 0; nf < 4; ++nf) {
                    acc[mf][nf] = __builtin_amdgcn_mfma_f32_16x16x32_bf16(a[mf][0], bfr[nf][0], acc[mf][nf], 0, 0, 0);
                    acc[mf][nf] = __builtin_amdgcn_mfma_f32_16x16x32_bf16(a[mf][1], bfr[nf][1], acc[mf][nf], 0, 0, 0);
                }
        }
    }
}

// epilogue: bf16 NHWC with relu (stage 1)
static __device__ __forceinline__ void store_t(
    u16* __restrict__ out, f4 acc[4][4], int b, int th0, int tw0, int wv, int ln, int quad)
{
#pragma unroll
    for (int mf = 0; mf < 4; ++mf)
#pragma unroll
        for (int nf = 0; nf < 4; ++nf) {
            f4 v = acc[mf][nf];
            ushort4 o;
            o.x = f2bu(fmaxf(v[0], 0.f)); o.y = f2bu(fmaxf(v[1], 0.f));
            o.z = f2bu(fmaxf(v[2], 0.f)); o.w = f2bu(fmaxf(v[3], 0.f));
            size_t pix = (size_t)b*HW_ + (th0 + wv*4 + nf)*W_ + tw0 + ln;
            *(ushort4*)(out + pix*64 + mf*16 + quad*4) = o;
        }
}

// epilogue: f32 NCHW + residual from bf16 NHWC (stage 2)
static __device__ __forceinline__ void store_f(
    float* __restrict__ out, const u16* __restrict__ resid_t,
    f4 acc[4][4], int b, int th0, int tw0, int wv, int ln, int quad)
{
#pragma unroll
    for (int mf = 0; mf < 4; ++mf)
#pragma unroll
        for (int nf = 0; nf < 4; ++nf) {
            size_t pix = (size_t)b*HW_ + (th0 + wv*4 + nf)*W_ + tw0 + ln;
            ushort4 rv = *(const ushort4*)(resid_t + pix*64 + mf*16 + quad*4);
            float rr[4] = {bu2f(rv.x), bu2f(rv.y), bu2f(rv.z), bu2f(rv.w)};
#pragma unroll
            for (int r = 0; r < 4; ++r) {
                int och = mf*16 + quad*4 + r;
                out[((size_t)b*C_ + och)*HW_ + (th0 + wv*4 + nf)*W_ + tw0 + ln]
                    = acc[mf][nf][r] + rr[r];
            }
        }
}

// ---------- fused stage: gauss(inA) + convA(plain, inA) + convB(PAC, inB | guide=inA) ----------
// STAGE1: relu + bf16 NHWC outs.   STAGE2: f32 NCHW outs + residuals.
// Round-0 config (2 blocks/CU, grid-limited) + T14 async restage of inB.
template<bool STAGE1>
__global__ __launch_bounds__(256, 2) void fused_stage(
    const u16* __restrict__ inA_t, const u16* __restrict__ inB_t,
    const u16* __restrict__ wA, const u16* __restrict__ wB,
    const float* __restrict__ biasA, const float* __restrict__ biasB,
    const u16* __restrict__ residA_t, const u16* __restrict__ residB_t,
    u16* __restrict__ outA_t, u16* __restrict__ outB_t,
    float* __restrict__ outA_f, float* __restrict__ outB_f)
{
    __shared__ u16   s_t[18*18*PITCH];   // 46656 B
    __shared__ float s_k[9*16*16];       //  9216 B  (55.9 KB total -> 2 blocks/CU)

    const int t    = threadIdx.x;
    const int b    = blockIdx.y;
    const int th0  = (blockIdx.x >> 3) * 16;
    const int tw0  = (blockIdx.x & 7) * 16;
    const int wv   = t >> 6;
    const int lane = t & 63;
    const int ln   = lane & 15;
    const int quad = lane >> 4;

    // ---- phase 1: stage guide/inA tile ----
    stage_tile(s_t, inA_t, b, th0, tw0, t);
    __syncthreads();

    // ---- phase 1b: ISSUE inB tile loads now; latency hides under gauss+convA ----
    uint4 hold[HOLD_K];
    stage_issue(hold, inB_t, b, th0, tw0, t);

    // ---- phase 2a: gaussian kernel from inA tile -> s_k (one pixel per thread) ----
    {
        const int px = t & 15, py = t >> 4;
        float d2[9];
#pragma unroll
        for (int p = 0; p < 9; ++p) d2[p] = 0.f;
        const u16* cb = &s_t[((py+1)*18 + (px+1))*PITCH];
#pragma unroll 1
        for (int co = 0; co < 8; ++co) {
            s8 c8 = *(const s8*)(cb + co*8);
            float cf[8];
#pragma unroll
            for (int j = 0; j < 8; ++j) cf[j] = bu2f((u16)c8[j]);
#pragma unroll
            for (int p = 0; p < 9; ++p) {
                s8 n8 = *(const s8*)(&s_t[((py + p/3)*18 + px + p%3)*PITCH + co*8]);
#pragma unroll
                for (int j = 0; j < 8; ++j) {
                    float d = bu2f((u16)n8[j]) - cf[j];
                    d2[p] += d * d;
                }
            }
        }
#pragma unroll
        for (int p = 0; p < 9; ++p)
            s_k[p*256 + py*16 + px] = __expf(-0.5f * d2[p]);
    }

    // ---- phase 2b: convA (plain) on inA tile ----
    {
        f4 acc[4][4];
        conv_core<false>(s_t, nullptr, wA, biasA, acc, wv, ln, quad);
        if (STAGE1) store_t(outA_t, acc, b, th0, tw0, wv, ln, quad);
        else        store_f(outA_f, residA_t, acc, b, th0, tw0, wv, ln, quad);
    }

    // ---- phase 3: commit held inB tile to LDS (orders s_k writes before reads too) ----
    __syncthreads();
    stage_commit(hold, s_t, t);
    __syncthreads();

    // ---- phase 4: convB (PAC with s_k) on inB tile ----
    {
        f4 acc[4][4];
        conv_core<true>(s_t, s_k, wB, biasB, acc, wv, ln, quad);
        if (STAGE1) store_t(outB_t, acc, b, th0, tw0, wv, ln, quad);
        else        store_f(outB_f, residB_t, acc, b, th0, tw0, wv, ln, quad);
    }
}

extern "C" void kernel_launch(void* const* d_in, const int* in_sizes, int n_in,
                              void* d_out, int out_size, void* d_ws, size_t ws_size,
                              hipStream_t stream)
{
    const float* x      = (const float*)d_in[0];
    const float* edge   = (const float*)d_in[1];
    const float* w_pac1 = (const float*)d_in[2];
    const float* b_pac1 = (const float*)d_in[3];
    const float* w_pac2 = (const float*)d_in[4];
    const float* b_pac2 = (const float*)d_in[5];
    const float* w_e1   = (const float*)d_in[6];
    const float* b_e1   = (const float*)d_in[7];
    const float* w_e2   = (const float*)d_in[8];
    const float* b_e2   = (const float*)d_in[9];

    float* out_sr   = (float*)d_out;
    float* out_edge = out_sr + (size_t)B_*C_*HW_;

    const size_t NT = (size_t)B_*HW_*64;
    // ws (67.4 MB): all intermediates live here — nothing parked in d_out.
    u16* x_t         = (u16*)d_ws;
    u16* edge_t      = x_t + NT;
    u16* res_edge1_t = edge_t + NT;
    u16* res_sr1_t   = res_edge1_t + NT;
    u16* w_t         = res_sr1_t + NT;    // [4][9][64][64]: 0=e1, 1=pac1, 2=e2, 3=pac2

    dim3 blk(256);

    transpose2<<<dim3(H_*8, B_, 2), blk, 0, stream>>>(x, edge, x_t, edge_t);
    wt_all<<<dim3(144, 4), blk, 0, stream>>>(w_e1, w_pac1, w_e2, w_pac2, w_t);

    // stage 1: gauss(edge)=kern1 (LDS-only) + conv_e1(edge) + pac1(x)
    fused_stage<true ><<<dim3(64, B_), blk, 0, stream>>>(
        edge_t, x_t, w_t + 0*WSZ, w_t + 1*WSZ, b_e1, b_pac1,
        nullptr, nullptr, res_edge1_t, res_sr1_t, nullptr, nullptr);
    // stage 2: gauss(res_edge1)=kern2 + conv_e2(res_edge1)+edge_resid + pac2(res_sr1)+x_resid
    fused_stage<false><<<dim3(64, B_), blk, 0, stream>>>(
        res_edge1_t, res_sr1_t, w_t + 2*WSZ, w_t + 3*WSZ, b_e2, b_pac2,
        edge_t, x_t, nullptr, nullptr, out_edge, out_sr);
}

// Round 4
// 255.960 us; speedup vs baseline: 1.3254x; 1.0359x over previous
//
#include <hip/hip_runtime.h>

typedef unsigned short u16;
typedef __attribute__((ext_vector_type(8))) short s8;   // 8 bf16 (4 VGPR) MFMA frag
typedef __attribute__((ext_vector_type(4))) float f4;   // 4 f32 acc frag

#define B_  8
#define C_  64
#define H_  128
#define W_  128
#define HW_ (H_*W_)
#define PITCH 72     // LDS shorts per pixel (144 B rows, 16B-aligned, uniform bank spread)
#define WSZ 36864    // elems of one transformed weight tensor [9][64][64]

// f32 -> bf16 bits, round-to-nearest-even (finite only)
static __device__ __forceinline__ u16 f2bu(float f) {
    union { float f; unsigned u; } c; c.f = f;
    unsigned u = c.u;
    u += 0x7fffu + ((u >> 16) & 1u);
    return (u16)(u >> 16);
}
static __device__ __forceinline__ float bu2f(u16 u) {
    union { unsigned u; float f; } c; c.u = ((unsigned)u) << 16; return c.f;
}
// f32 <-> f16 (gaussian kernel LDS store; 2^-11 rel err << bf16 path error; verified round 2)
static __device__ __forceinline__ u16 f2h(float f) {
    union { _Float16 h; u16 u; } c; c.h = (_Float16)f; return c.u;
}
static __device__ __forceinline__ float h2f(u16 u) {
    union { u16 u; _Float16 h; } c; c.u = u; return (float)c.h;
}

// ---------- transpose+cast: [b][c][h][w] f32 -> [b][h][w][c] bf16 ----------
__global__ __launch_bounds__(256) void transpose2(
    const float* __restrict__ x, const float* __restrict__ edge,
    u16* __restrict__ x_t, u16* __restrict__ edge_t)
{
    __shared__ float s[16][68];
    const int t  = threadIdx.x;
    const int h  = blockIdx.x >> 3;
    const int w0 = (blockIdx.x & 7) * 16;
    const int b  = blockIdx.y;
    const float* src = blockIdx.z ? edge : x;
    u16* dst = blockIdx.z ? edge_t : x_t;
    {
        int c = t >> 2, wq = t & 3;
        float4 v = *(const float4*)(src + ((size_t)b*C_ + c)*HW_ + h*W_ + w0 + wq*4);
        s[wq*4+0][c] = v.x; s[wq*4+1][c] = v.y; s[wq*4+2][c] = v.z; s[wq*4+3][c] = v.w;
    }
    __syncthreads();
    {
        int w = t >> 4, cg = t & 15;
        float4 v = *(const float4*)(&s[w][cg*4]);
        ushort4 o; o.x = f2bu(v.x); o.y = f2bu(v.y); o.z = f2bu(v.z); o.w = f2bu(v.w);
        *(ushort4*)(dst + ((size_t)b*HW_ + h*W_ + w0 + w)*64 + cg*4) = o;
    }
}

// ---------- weight transform: 4x [o][c][3][3] f32 -> [cid][p][o][c] bf16 ----------
__global__ __launch_bounds__(256) void wt_all(
    const float* __restrict__ w0, const float* __restrict__ w1,
    const float* __restrict__ w2, const float* __restrict__ w3,
    u16* __restrict__ dst)
{
    int idx = blockIdx.x*256 + threadIdx.x;            // 0..36863
    int cid = blockIdx.y;
    const float* w = (cid == 0) ? w0 : (cid == 1) ? w1 : (cid == 2) ? w2 : w3;
    int p = idx >> 12, o = (idx >> 6) & 63, c = idx & 63;
    dst[(size_t)cid*WSZ + idx] = f2bu(w[((size_t)o*64 + c)*9 + p]);
}

// ---------- helpers for the fused kernel ----------
static __device__ __forceinline__ void stage_tile(
    u16* __restrict__ s_t, const u16* __restrict__ src, int b, int th0, int tw0, int t)
{
    for (int i = t; i < 18*18*8; i += 256) {
        int pix = i >> 3, ch = i & 7;
        int rr = pix / 18, ww = pix - rr*18;
        int gr = th0 + rr - 1, gw = tw0 + ww - 1;
        uint4 v = {0u,0u,0u,0u};
        if ((unsigned)gr < (unsigned)H_ && (unsigned)gw < (unsigned)W_)
            v = *(const uint4*)(src + ((size_t)b*HW_ + gr*W_ + gw)*64 + ch*8);
        *(uint4*)(&s_t[pix*PITCH + ch*8]) = v;
    }
}

// conv core (och-split): D = sum_p [kern_p ⊙] W_p[32och,64c] x X_p[64c,256px].
// Block owns och [ocOff, ocOff+32); wave wv owns pixel rows wv*4+nf (unchanged map).
template<bool PAC>
static __device__ __forceinline__ void conv_core(
    const u16* __restrict__ s_t, const u16* __restrict__ s_k,
    const u16* __restrict__ w, const float* __restrict__ bias,
    f4 acc[2][4], int ocOff, int wv, int ln, int quad)
{
#pragma unroll
    for (int mf = 0; mf < 2; ++mf) {
        f4 bv;
#pragma unroll
        for (int r = 0; r < 4; ++r) bv[r] = bias[ocOff + mf*16 + quad*4 + r];
#pragma unroll
        for (int nf = 0; nf < 4; ++nf) acc[mf][nf] = bv;
    }

#pragma unroll
    for (int p = 0; p < 9; ++p) {
        const int dr = p / 3, dc = p - dr*3;
        s8 a[2][2];
#pragma unroll
        for (int mf = 0; mf < 2; ++mf)
#pragma unroll
            for (int kc = 0; kc < 2; ++kc)
                a[mf][kc] = *(const s8*)(w + (((size_t)p*64 + ocOff + mf*16 + ln)*64 + kc*32 + quad*8));
        s8 bfr[4][2];
#pragma unroll
        for (int nf = 0; nf < 4; ++nf) {
            const u16* base = &s_t[((wv*4 + nf + dr)*18 + ln + dc)*PITCH];
#pragma unroll
            for (int kc = 0; kc < 2; ++kc)
                bfr[nf][kc] = *(const s8*)(base + kc*32 + quad*8);
        }
        if (PAC) {
            float kv[4];
#pragma unroll
            for (int nf = 0; nf < 4; ++nf)
                kv[nf] = h2f(s_k[p*256 + (wv*4 + nf)*16 + ln]);
#pragma unroll
            for (int mf = 0; mf < 2; ++mf)
#pragma unroll
                for (int nf = 0; nf < 4; ++nf) {
                    f4 d = {0.f, 0.f, 0.f, 0.f};
                    d = __builtin_amdgcn_mfma_f32_16x16x32_bf16(a[mf][0], bfr[nf][0], d, 0, 0, 0);
                    d = __builtin_amdgcn_mfma_f32_16x16x32_bf16(a[mf][1], bfr[nf][1], d, 0, 0, 0);
                    acc[mf][nf] += kv[nf] * d;
                }
        } else {
#pragma unroll
            for (int mf = 0; mf < 2; ++mf)
#pragma unroll
                for (int nf = 0; nf < 4; ++nf) {
                    acc[mf][nf] = __builtin_amdgcn_mfma_f32_16x16x32_bf16(a[mf][0], bfr[nf][0], acc[mf][nf], 0, 0, 0);
                    acc[mf][nf] = __builtin_amdgcn_mfma_f32_16x16x32_bf16(a[mf][1], bfr[nf][1], acc[mf][nf], 0, 0, 0);
                }
        }
    }
}

// epilogue: bf16 NHWC with relu (stage 1), och half [ocOff, ocOff+32)
static __device__ __forceinline__ void store_t(
    u16* __restrict__ out, f4 acc[2][4], int b, int th0, int tw0,
    int ocOff, int wv, int ln, int quad)
{
#pragma unroll
    for (int mf = 0; mf < 2; ++mf)
#pragma unroll
        for (int nf = 0; nf < 4; ++nf) {
            f4 v = acc[mf][nf];
            ushort4 o;
            o.x = f2bu(fmaxf(v[0], 0.f)); o.y = f2bu(fmaxf(v[1], 0.f));
            o.z = f2bu(fmaxf(v[2], 0.f)); o.w = f2bu(fmaxf(v[3], 0.f));
            size_t pix = (size_t)b*HW_ + (th0 + wv*4 + nf)*W_ + tw0 + ln;
            *(ushort4*)(out + pix*64 + ocOff + mf*16 + quad*4) = o;
        }
}

// epilogue: f32 NCHW + residual from bf16 NHWC (stage 2), och half [ocOff, ocOff+32)
static __device__ __forceinline__ void store_f(
    float* __restrict__ out, const u16* __restrict__ resid_t,
    f4 acc[2][4], int b, int th0, int tw0, int ocOff, int wv, int ln, int quad)
{
#pragma unroll
    for (int mf = 0; mf < 2; ++mf)
#pragma unroll
        for (int nf = 0; nf < 4; ++nf) {
            size_t pix = (size_t)b*HW_ + (th0 + wv*4 + nf)*W_ + tw0 + ln;
            ushort4 rv = *(const ushort4*)(resid_t + pix*64 + ocOff + mf*16 + quad*4);
            float rr[4] = {bu2f(rv.x), bu2f(rv.y), bu2f(rv.z), bu2f(rv.w)};
#pragma unroll
            for (int r = 0; r < 4; ++r) {
                int och = ocOff + mf*16 + quad*4 + r;
                out[((size_t)b*C_ + och)*HW_ + (th0 + wv*4 + nf)*W_ + tw0 + ln]
                    = acc[mf][nf][r] + rr[r];
            }
        }
}

// ---------- fused stage: gauss(inA) + convA(plain, inA) + convB(PAC, inB | guide=inA) ----------
// och-split 2-way: grid 1024, LDS 51264 B -> 3 blocks/CU resident (12 waves/CU).
// Block index encodes XCD pairing: the two och-halves of a tile are 8 dispatches
// apart => same XCD => second half's tile stage hits L2, not HBM.
template<bool STAGE1>
__global__ __launch_bounds__(256, 2) void fused_stage(
    const u16* __restrict__ inA_t, const u16* __restrict__ inB_t,
    const u16* __restrict__ wA, const u16* __restrict__ wB,
    const float* __restrict__ biasA, const float* __restrict__ biasB,
    const u16* __restrict__ residA_t, const u16* __restrict__ residB_t,
    u16* __restrict__ outA_t, u16* __restrict__ outB_t,
    float* __restrict__ outA_f, float* __restrict__ outB_f)
{
    __shared__ u16 s_t[18*18*PITCH];   // 46656 B
    __shared__ u16 s_k[9*256];         //  4608 B (fp16)  -> 51264 B total

    const int t    = threadIdx.x;
    // L -> (tileb, och): pair (tileb,0)/(tileb,1) are 8 dispatches apart (same XCD slot)
    const int L    = blockIdx.x;                 // 0..1023
    const int tb   = ((L >> 4) << 3) | (L & 7);  // 0..511
    const int och  = (L >> 3) & 1;
    const int ocOff= och * 32;
    const int tile = tb & 63;
    const int b    = tb >> 6;
    const int th0  = (tile >> 3) * 16;
    const int tw0  = (tile & 7) * 16;
    const int wv   = t >> 6;
    const int lane = t & 63;
    const int ln   = lane & 15;
    const int quad = lane >> 4;

    // ---- phase 1: stage guide/inA tile ----
    stage_tile(s_t, inA_t, b, th0, tw0, t);
    __syncthreads();

    // ---- phase 2a: gaussian kernel from inA tile -> s_k (one pixel per thread) ----
    // (computed by both och-halves; ~LDS-only, cheap, avoids inter-block ordering)
    {
        const int px = t & 15, py = t >> 4;
        float d2[9];
#pragma unroll
        for (int p = 0; p < 9; ++p) d2[p] = 0.f;
        const u16* cb = &s_t[((py+1)*18 + (px+1))*PITCH];
#pragma unroll 1
        for (int co = 0; co < 8; ++co) {
            s8 c8 = *(const s8*)(cb + co*8);
            float cf[8];
#pragma unroll
            for (int j = 0; j < 8; ++j) cf[j] = bu2f((u16)c8[j]);
#pragma unroll
            for (int p = 0; p < 9; ++p) {
                s8 n8 = *(const s8*)(&s_t[((py + p/3)*18 + px + p%3)*PITCH + co*8]);
#pragma unroll
                for (int j = 0; j < 8; ++j) {
                    float d = bu2f((u16)n8[j]) - cf[j];
                    d2[p] += d * d;
                }
            }
        }
#pragma unroll
        for (int p = 0; p < 9; ++p)
            s_k[p*256 + py*16 + px] = f2h(__expf(-0.5f * d2[p]));
    }

    // ---- phase 2b: convA (plain) on inA tile ----
    {
        f4 acc[2][4];
        conv_core<false>(s_t, nullptr, wA, biasA, acc, ocOff, wv, ln, quad);
        if (STAGE1) store_t(outA_t, acc, b, th0, tw0, ocOff, wv, ln, quad);
        else        store_f(outA_f, residA_t, acc, b, th0, tw0, ocOff, wv, ln, quad);
    }

    // ---- phase 3: restage with inB tile (also orders s_k writes before reads) ----
    __syncthreads();
    stage_tile(s_t, inB_t, b, th0, tw0, t);
    __syncthreads();

    // ---- phase 4: convB (PAC with s_k) on inB tile ----
    {
        f4 acc[2][4];
        conv_core<true>(s_t, s_k, wB, biasB, acc, ocOff, wv, ln, quad);
        if (STAGE1) store_t(outB_t, acc, b, th0, tw0, ocOff, wv, ln, quad);
        else        store_f(outB_f, residB_t, acc, b, th0, tw0, ocOff, wv, ln, quad);
    }
}

extern "C" void kernel_launch(void* const* d_in, const int* in_sizes, int n_in,
                              void* d_out, int out_size, void* d_ws, size_t ws_size,
                              hipStream_t stream)
{
    const float* x      = (const float*)d_in[0];
    const float* edge   = (const float*)d_in[1];
    const float* w_pac1 = (const float*)d_in[2];
    const float* b_pac1 = (const float*)d_in[3];
    const float* w_pac2 = (const float*)d_in[4];
    const float* b_pac2 = (const float*)d_in[5];
    const float* w_e1   = (const float*)d_in[6];
    const float* b_e1   = (const float*)d_in[7];
    const float* w_e2   = (const float*)d_in[8];
    const float* b_e2   = (const float*)d_in[9];

    float* out_sr   = (float*)d_out;
    float* out_edge = out_sr + (size_t)B_*C_*HW_;

    const size_t NT = (size_t)B_*HW_*64;
    // ws (67.4 MB): all intermediates live here — nothing parked in d_out.
    u16* x_t         = (u16*)d_ws;
    u16* edge_t      = x_t + NT;
    u16* res_edge1_t = edge_t + NT;
    u16* res_sr1_t   = res_edge1_t + NT;
    u16* w_t         = res_sr1_t + NT;    // [4][9][64][64]: 0=e1, 1=pac1, 2=e2, 3=pac2

    dim3 blk(256);

    transpose2<<<dim3(H_*8, B_, 2), blk, 0, stream>>>(x, edge, x_t, edge_t);
    wt_all<<<dim3(144, 4), blk, 0, stream>>>(w_e1, w_pac1, w_e2, w_pac2, w_t);

    // stage 1: gauss(edge)=kern1 (LDS-only) + conv_e1(edge) + pac1(x)
    fused_stage<true ><<<dim3(1024), blk, 0, stream>>>(
        edge_t, x_t, w_t + 0*WSZ, w_t + 1*WSZ, b_e1, b_pac1,
        nullptr, nullptr, res_edge1_t, res_sr1_t, nullptr, nullptr);
    // stage 2: gauss(res_edge1)=kern2 + conv_e2(res_edge1)+edge_resid + pac2(res_sr1)+x_resid
    fused_stage<false><<<dim3(1024), blk, 0, stream>>>(
        res_edge1_t, res_sr1_t, w_t + 2*WSZ, w_t + 3*WSZ, b_e2, b_pac2,
        edge_t, x_t, nullptr, nullptr, out_edge, out_sr);
}

// Round 5
// 238.943 us; speedup vs baseline: 1.4198x; 1.0712x over previous
//
#include <hip/hip_runtime.h>

typedef unsigned short u16;
typedef __attribute__((ext_vector_type(8))) short s8;   // 8 bf16 (4 VGPR) MFMA frag
typedef __attribute__((ext_vector_type(4))) float f4;   // 4 f32 acc frag

#define B_  8
#define C_  64
#define H_  128
#define W_  128
#define HW_ (H_*W_)
#define PITCH 72     // LDS shorts per pixel (144 B rows, 16B-aligned, uniform bank spread)
#define WSZ 36864    // elems of one transformed weight tensor [9][64][64]

// tile: 8 rows x 16 cols output, halo 10 x 18. Grid 2048.
// LDS 30528 B + VGPR<=128 -> 4 blocks/CU resident (16 waves/CU), no work duplication.
// Default dispatch order pins XCD = tile column -> vertical halo neighbors share L2.

// f32 -> bf16 bits, round-to-nearest-even (finite only)
static __device__ __forceinline__ u16 f2bu(float f) {
    union { float f; unsigned u; } c; c.f = f;
    unsigned u = c.u;
    u += 0x7fffu + ((u >> 16) & 1u);
    return (u16)(u >> 16);
}
static __device__ __forceinline__ float bu2f(u16 u) {
    union { unsigned u; float f; } c; c.u = ((unsigned)u) << 16; return c.f;
}

// ---------- transpose+cast: [b][c][h][w] f32 -> [b][h][w][c] bf16 ----------
__global__ __launch_bounds__(256) void transpose2(
    const float* __restrict__ x, const float* __restrict__ edge,
    u16* __restrict__ x_t, u16* __restrict__ edge_t)
{
    __shared__ float s[16][68];
    const int t  = threadIdx.x;
    const int h  = blockIdx.x >> 3;
    const int w0 = (blockIdx.x & 7) * 16;
    const int b  = blockIdx.y;
    const float* src = blockIdx.z ? edge : x;
    u16* dst = blockIdx.z ? edge_t : x_t;
    {
        int c = t >> 2, wq = t & 3;
        float4 v = *(const float4*)(src + ((size_t)b*C_ + c)*HW_ + h*W_ + w0 + wq*4);
        s[wq*4+0][c] = v.x; s[wq*4+1][c] = v.y; s[wq*4+2][c] = v.z; s[wq*4+3][c] = v.w;
    }
    __syncthreads();
    {
        int w = t >> 4, cg = t & 15;
        float4 v = *(const float4*)(&s[w][cg*4]);
        ushort4 o; o.x = f2bu(v.x); o.y = f2bu(v.y); o.z = f2bu(v.z); o.w = f2bu(v.w);
        *(ushort4*)(dst + ((size_t)b*HW_ + h*W_ + w0 + w)*64 + cg*4) = o;
    }
}

// ---------- weight transform: 4x [o][c][3][3] f32 -> [cid][p][o][c] bf16 ----------
__global__ __launch_bounds__(256) void wt_all(
    const float* __restrict__ w0, const float* __restrict__ w1,
    const float* __restrict__ w2, const float* __restrict__ w3,
    u16* __restrict__ dst)
{
    int idx = blockIdx.x*256 + threadIdx.x;            // 0..36863
    int cid = blockIdx.y;
    const float* w = (cid == 0) ? w0 : (cid == 1) ? w1 : (cid == 2) ? w2 : w3;
    int p = idx >> 12, o = (idx >> 6) & 63, c = idx & 63;
    dst[(size_t)cid*WSZ + idx] = f2bu(w[((size_t)o*64 + c)*9 + p]);
}

// ---------- helpers for the fused kernel ----------
static __device__ __forceinline__ void stage_tile(
    u16* __restrict__ s_t, const u16* __restrict__ src, int b, int th0, int tw0, int t)
{
    for (int i = t; i < 10*18*8; i += 256) {
        int pix = i >> 3, ch = i & 7;
        int rr = pix / 18, ww = pix - rr*18;
        int gr = th0 + rr - 1, gw = tw0 + ww - 1;
        uint4 v = {0u,0u,0u,0u};
        if ((unsigned)gr < (unsigned)H_ && (unsigned)gw < (unsigned)W_)
            v = *(const uint4*)(src + ((size_t)b*HW_ + gr*W_ + gw)*64 + ch*8);
        *(uint4*)(&s_t[pix*PITCH + ch*8]) = v;
    }
}

// conv core: D = sum_p [kern_p ⊙] W_p[32och,64c] x X_p[64c,64px], f32 acc, bias init.
// wave (wvM,wvN): och half wvM, pixel rows wvN*4+nf; frag maps verified (rounds 1/4).
template<bool PAC>
static __device__ __forceinline__ void conv_core(
    const u16* __restrict__ s_t, const float* __restrict__ s_k,
    const u16* __restrict__ w, const float* __restrict__ bias,
    f4 acc[2][4], int wvM, int wvN, int ln, int quad)
{
#pragma unroll
    for (int mf = 0; mf < 2; ++mf) {
        f4 bv;
#pragma unroll
        for (int r = 0; r < 4; ++r) bv[r] = bias[wvM*32 + mf*16 + quad*4 + r];
#pragma unroll
        for (int nf = 0; nf < 4; ++nf) acc[mf][nf] = bv;
    }

#pragma unroll
    for (int p = 0; p < 9; ++p) {
        const int dr = p / 3, dc = p - dr*3;
        s8 a[2][2];
#pragma unroll
        for (int mf = 0; mf < 2; ++mf)
#pragma unroll
            for (int kc = 0; kc < 2; ++kc)
                a[mf][kc] = *(const s8*)(w + (((size_t)p*64 + wvM*32 + mf*16 + ln)*64 + kc*32 + quad*8));
        s8 bfr[4][2];
#pragma unroll
        for (int nf = 0; nf < 4; ++nf) {
            const u16* base = &s_t[((wvN*4 + nf + dr)*18 + ln + dc)*PITCH];
#pragma unroll
            for (int kc = 0; kc < 2; ++kc)
                bfr[nf][kc] = *(const s8*)(base + kc*32 + quad*8);
        }
        if (PAC) {
            float kv[4];
#pragma unroll
            for (int nf = 0; nf < 4; ++nf)
                kv[nf] = s_k[p*128 + (wvN*4 + nf)*16 + ln];
#pragma unroll
            for (int mf = 0; mf < 2; ++mf)
#pragma unroll
                for (int nf = 0; nf < 4; ++nf) {
                    f4 d = {0.f, 0.f, 0.f, 0.f};
                    d = __builtin_amdgcn_mfma_f32_16x16x32_bf16(a[mf][0], bfr[nf][0], d, 0, 0, 0);
                    d = __builtin_amdgcn_mfma_f32_16x16x32_bf16(a[mf][1], bfr[nf][1], d, 0, 0, 0);
                    acc[mf][nf] += kv[nf] * d;
                }
        } else {
#pragma unroll
            for (int mf = 0; mf < 2; ++mf)
#pragma unroll
                for (int nf = 0; nf < 4; ++nf) {
                    acc[mf][nf] = __builtin_amdgcn_mfma_f32_16x16x32_bf16(a[mf][0], bfr[nf][0], acc[mf][nf], 0, 0, 0);
                    acc[mf][nf] = __builtin_amdgcn_mfma_f32_16x16x32_bf16(a[mf][1], bfr[nf][1], acc[mf][nf], 0, 0, 0);
                }
        }
    }
}

// epilogue: bf16 NHWC with relu (stage 1)
static __device__ __forceinline__ void store_t(
    u16* __restrict__ out, f4 acc[2][4], int b, int th0, int tw0,
    int wvM, int wvN, int ln, int quad)
{
#pragma unroll
    for (int mf = 0; mf < 2; ++mf)
#pragma unroll
        for (int nf = 0; nf < 4; ++nf) {
            f4 v = acc[mf][nf];
            ushort4 o;
            o.x = f2bu(fmaxf(v[0], 0.f)); o.y = f2bu(fmaxf(v[1], 0.f));
            o.z = f2bu(fmaxf(v[2], 0.f)); o.w = f2bu(fmaxf(v[3], 0.f));
            size_t pix = (size_t)b*HW_ + (th0 + wvN*4 + nf)*W_ + tw0 + ln;
            *(ushort4*)(out + pix*64 + wvM*32 + mf*16 + quad*4) = o;
        }
}

// epilogue: f32 NCHW + residual from bf16 NHWC (stage 2)
static __device__ __forceinline__ void store_f(
    float* __restrict__ out, const u16* __restrict__ resid_t,
    f4 acc[2][4], int b, int th0, int tw0, int wvM, int wvN, int ln, int quad)
{
#pragma unroll
    for (int mf = 0; mf < 2; ++mf)
#pragma unroll
        for (int nf = 0; nf < 4; ++nf) {
            size_t pix = (size_t)b*HW_ + (th0 + wvN*4 + nf)*W_ + tw0 + ln;
            ushort4 rv = *(const ushort4*)(resid_t + pix*64 + wvM*32 + mf*16 + quad*4);
            float rr[4] = {bu2f(rv.x), bu2f(rv.y), bu2f(rv.z), bu2f(rv.w)};
#pragma unroll
            for (int r = 0; r < 4; ++r) {
                int och = wvM*32 + mf*16 + quad*4 + r;
                out[((size_t)b*C_ + och)*HW_ + (th0 + wvN*4 + nf)*W_ + tw0 + ln]
                    = acc[mf][nf][r] + rr[r];
            }
        }
}

// ---------- fused stage: gauss(inA) + convA(plain, inA) + convB(PAC, inB | guide=inA) ----------
// STAGE1: relu + bf16 NHWC outs.   STAGE2: f32 NCHW outs + residuals.
// NOTE launch_bounds(256,2): VGPR cap 256, allocator lands ~128 naturally.
// (256,4) forces VGPR=64 -> ~64 regs spilled/thread -> +130 MB scratch writes (round 1).
template<bool STAGE1>
__global__ __launch_bounds__(256, 2) void fused_stage(
    const u16* __restrict__ inA_t, const u16* __restrict__ inB_t,
    const u16* __restrict__ wA, const u16* __restrict__ wB,
    const float* __restrict__ biasA, const float* __restrict__ biasB,
    const u16* __restrict__ residA_t, const u16* __restrict__ residB_t,
    u16* __restrict__ outA_t, u16* __restrict__ outB_t,
    float* __restrict__ outA_f, float* __restrict__ outB_f)
{
    __shared__ u16   s_t[10*18*PITCH];   // 25920 B
    __shared__ float s_k[9*128];         //  4608 B  (30528 B total -> 4+ blocks/CU by LDS)

    const int t    = threadIdx.x;
    const int b    = blockIdx.y;
    const int th0  = (blockIdx.x >> 3) * 8;
    const int tw0  = (blockIdx.x & 7) * 16;
    const int wv   = t >> 6;
    const int wvM  = wv >> 1;            // och half (0..1)
    const int wvN  = wv & 1;             // pixel-row half (0..1)
    const int lane = t & 63;
    const int ln   = lane & 15;
    const int quad = lane >> 4;

    // ---- phase 1: stage guide/inA tile ----
    stage_tile(s_t, inA_t, b, th0, tw0, t);
    __syncthreads();

    // ---- phase 2a: gaussian kernel from inA tile -> s_k ----
    // 128 pixels, 256 threads: thread owns pixel (t&127) and taps p0..p0+np-1.
    {
        const int px   = t & 127;
        const int half = t >> 7;
        const int p0   = half ? 5 : 0;
        const int np   = half ? 4 : 5;
        const int py   = px >> 4, pxc = px & 15;
        float d2[5];
#pragma unroll
        for (int k = 0; k < 5; ++k) d2[k] = 0.f;
        const u16* cb = &s_t[((py+1)*18 + (pxc+1))*PITCH];
#pragma unroll 1
        for (int co = 0; co < 8; ++co) {
            s8 c8 = *(const s8*)(cb + co*8);
            float cf[8];
#pragma unroll
            for (int j = 0; j < 8; ++j) cf[j] = bu2f((u16)c8[j]);
#pragma unroll
            for (int k = 0; k < 5; ++k) {
                if (k < np) {
                    int p = p0 + k;
                    int dr = p / 3, dc = p - dr*3;
                    s8 n8 = *(const s8*)(&s_t[((py + dr)*18 + pxc + dc)*PITCH + co*8]);
#pragma unroll
                    for (int j = 0; j < 8; ++j) {
                        float d = bu2f((u16)n8[j]) - cf[j];
                        d2[k] += d * d;
                    }
                }
            }
        }
#pragma unroll
        for (int k = 0; k < 5; ++k)
            if (k < np) s_k[(p0+k)*128 + px] = __expf(-0.5f * d2[k]);
    }

    // ---- phase 2b: convA (plain) on inA tile ----
    {
        f4 acc[2][4];
        conv_core<false>(s_t, nullptr, wA, biasA, acc, wvM, wvN, ln, quad);
        if (STAGE1) store_t(outA_t, acc, b, th0, tw0, wvM, wvN, ln, quad);
        else        store_f(outA_f, residA_t, acc, b, th0, tw0, wvM, wvN, ln, quad);
    }

    // ---- phase 3: restage with inB tile (also orders s_k writes before reads) ----
    __syncthreads();
    stage_tile(s_t, inB_t, b, th0, tw0, t);
    __syncthreads();

    // ---- phase 4: convB (PAC with s_k) on inB tile ----
    {
        f4 acc[2][4];
        conv_core<true>(s_t, s_k, wB, biasB, acc, wvM, wvN, ln, quad);
        if (STAGE1) store_t(outB_t, acc, b, th0, tw0, wvM, wvN, ln, quad);
        else        store_f(outB_f, residB_t, acc, b, th0, tw0, wvM, wvN, ln, quad);
    }
}

extern "C" void kernel_launch(void* const* d_in, const int* in_sizes, int n_in,
                              void* d_out, int out_size, void* d_ws, size_t ws_size,
                              hipStream_t stream)
{
    const float* x      = (const float*)d_in[0];
    const float* edge   = (const float*)d_in[1];
    const float* w_pac1 = (const float*)d_in[2];
    const float* b_pac1 = (const float*)d_in[3];
    const float* w_pac2 = (const float*)d_in[4];
    const float* b_pac2 = (const float*)d_in[5];
    const float* w_e1   = (const float*)d_in[6];
    const float* b_e1   = (const float*)d_in[7];
    const float* w_e2   = (const float*)d_in[8];
    const float* b_e2   = (const float*)d_in[9];

    float* out_sr   = (float*)d_out;
    float* out_edge = out_sr + (size_t)B_*C_*HW_;

    const size_t NT = (size_t)B_*HW_*64;
    // ws (67.4 MB): all intermediates live here — nothing parked in d_out.
    u16* x_t         = (u16*)d_ws;
    u16* edge_t      = x_t + NT;
    u16* res_edge1_t = edge_t + NT;
    u16* res_sr1_t   = res_edge1_t + NT;
    u16* w_t         = res_sr1_t + NT;    // [4][9][64][64]: 0=e1, 1=pac1, 2=e2, 3=pac2

    dim3 blk(256);

    transpose2<<<dim3(H_*8, B_, 2), blk, 0, stream>>>(x, edge, x_t, edge_t);
    wt_all<<<dim3(144, 4), blk, 0, stream>>>(w_e1, w_pac1, w_e2, w_pac2, w_t);

    // stage 1: gauss(edge)=kern1 (LDS-only) + conv_e1(edge) + pac1(x)
    fused_stage<true ><<<dim3(128, B_), blk, 0, stream>>>(
        edge_t, x_t, w_t + 0*WSZ, w_t + 1*WSZ, b_e1, b_pac1,
        nullptr, nullptr, res_edge1_t, res_sr1_t, nullptr, nullptr);
    // stage 2: gauss(res_edge1)=kern2 + conv_e2(res_edge1)+edge_resid + pac2(res_sr1)+x_resid
    fused_stage<false><<<dim3(128, B_), blk, 0, stream>>>(
        res_edge1_t, res_sr1_t, w_t + 2*WSZ, w_t + 3*WSZ, b_e2, b_pac2,
        edge_t, x_t, nullptr, nullptr, out_edge, out_sr);
}